// Round 3
// baseline (403.193 us; speedup 1.0000x reference)
//
#include <hip/hip_runtime.h>
#include <stdint.h>

#define T_ 2048
#define C_ 1024
#define H_ 16
#define HD_ 64

typedef __attribute__((ext_vector_type(8))) short bf16x8;
typedef __attribute__((ext_vector_type(4))) float f32x4;

__device__ __forceinline__ unsigned short f2b(float f) {
  union { float f; unsigned u; } v; v.f = f;
  return (unsigned short)((v.u + 0x7fffu + ((v.u >> 16) & 1u)) >> 16);
}

// ---------------- conversion kernels ----------------
__global__ void cvt_f32_bf16(const float* __restrict__ in, unsigned short* __restrict__ out, int n4) {
  int stride = gridDim.x * blockDim.x;
  for (int i = blockIdx.x * blockDim.x + threadIdx.x; i < n4; i += stride) {
    float4 v = ((const float4*)in)[i];
    ushort4 o;
    o.x = f2b(v.x); o.y = f2b(v.y); o.z = f2b(v.z); o.w = f2b(v.w);
    ((ushort4*)out)[i] = o;
  }
}

// in: fp32 [K][N] row-major  ->  out: bf16 [N][K] row-major
__global__ void transpose_cvt(const float* __restrict__ in, unsigned short* __restrict__ out, int K, int N) {
  __shared__ float tile[32][33];
  int k0 = blockIdx.x * 32, n0 = blockIdx.y * 32;
  int tx = threadIdx.x & 31, ty = threadIdx.x >> 5;
#pragma unroll
  for (int i = 0; i < 4; ++i)
    tile[ty + i*8][tx] = in[(size_t)(k0 + ty + i*8) * N + n0 + tx];
  __syncthreads();
#pragma unroll
  for (int i = 0; i < 4; ++i)
    out[(size_t)(n0 + ty + i*8) * K + k0 + tx] = f2b(tile[tx][ty + i*8]);
}

// ---------------- GEMM: C[M,N] = A[M,K] * Bt[N,K]^T (+bias) ----------------
// 128x128 tile, BK=32, 4 waves (2x2), global_load_lds staging with
// pre-swizzled global source (16B-unit swizzle: unit ^= (row>>1)&3 -> 2-way max).
#define GL16(g, l) __builtin_amdgcn_global_load_lds((const __attribute__((address_space(1))) void*)(g), (__attribute__((address_space(3))) void*)(l), 16, 0, 0)

template<int EPI>  // 0 = proj (fp32 out + bias), 1 = qkv split epilogue
__global__ __launch_bounds__(256) void gemm128(
    const unsigned short* __restrict__ A,
    const unsigned short* __restrict__ Bt,
    const float* __restrict__ bias,
    float* __restrict__ outF,
    unsigned short* __restrict__ outQ,
    unsigned short* __restrict__ outK,
    unsigned short* __restrict__ outV,
    int M, int N, int K)
{
  __shared__ __align__(16) unsigned short Al[2][128*32];
  __shared__ __align__(16) unsigned short Bl[2][128*32];
  const int tid = threadIdx.x, lane = tid & 63, w = tid >> 6;
  const int wm = w >> 1, wn = w & 1;
  const int m0 = blockIdx.x * 128, n0 = blockIdx.y * 128;

  f32x4 acc[4][4];
#pragma unroll
  for (int i = 0; i < 4; ++i)
#pragma unroll
    for (int j = 0; j < 4; ++j)
      acc[i][j] = (f32x4)0.0f;

  const int NT = K >> 5;
  const int srow = lane >> 2;   // row-within-chunk (4 lanes per 64B row)
  const int punit = lane & 3;   // physical 16B unit within row

  // prologue stage: kt=0 -> buf 0
#pragma unroll
  for (int i = 0; i < 2; ++i) {
    int chunk = w*2 + i;
    int row = chunk*16 + srow;
    int lu = punit ^ ((row >> 1) & 3);
    GL16(A  + (size_t)(m0 + row) * K + lu*8, &Al[0][chunk*512]);
    GL16(Bt + (size_t)(n0 + row) * K + lu*8, &Bl[0][chunk*512]);
  }
  __syncthreads();

  for (int kt = 0; kt < NT; ++kt) {
    if (kt + 1 < NT) {
      int nb = (kt+1) & 1;
#pragma unroll
      for (int i = 0; i < 2; ++i) {
        int chunk = w*2 + i;
        int row = chunk*16 + srow;
        int lu = punit ^ ((row >> 1) & 3);
        GL16(A  + (size_t)(m0 + row) * K + ((kt+1) << 5) + lu*8, &Al[nb][chunk*512]);
        GL16(Bt + (size_t)(n0 + row) * K + ((kt+1) << 5) + lu*8, &Bl[nb][chunk*512]);
      }
    }
    {
      const int cb = kt & 1;
      const int r16 = lane & 15, u = lane >> 4;
      bf16x8 af[4], bfr[4];
#pragma unroll
      for (int f = 0; f < 4; ++f) {
        int ra = wm*64 + f*16 + r16;
        af[f]  = *(const bf16x8*)&Al[cb][ra*32 + ((u ^ ((ra>>1)&3)) << 3)];
        int rb = wn*64 + f*16 + r16;
        bfr[f] = *(const bf16x8*)&Bl[cb][rb*32 + ((u ^ ((rb>>1)&3)) << 3)];
      }
#pragma unroll
      for (int i = 0; i < 4; ++i)
#pragma unroll
        for (int j = 0; j < 4; ++j)
          acc[i][j] = __builtin_amdgcn_mfma_f32_16x16x32_bf16(af[i], bfr[j], acc[i][j], 0, 0, 0);
    }
    __syncthreads();
  }

  // epilogue: D mapping col=lane&15, row=(lane>>4)*4+r
  const int u = lane >> 4, r16 = lane & 15;
#pragma unroll
  for (int i = 0; i < 4; ++i) {
    int rbase = m0 + wm*64 + i*16 + u*4;
#pragma unroll
    for (int j = 0; j < 4; ++j) {
      int col = n0 + wn*64 + j*16 + r16;
      float bv = bias[col];
      if (EPI == 0) {
#pragma unroll
        for (int r = 0; r < 4; ++r)
          outF[(size_t)(rbase + r) * N + col] = acc[i][j][r] + bv;
      } else {
        int sec = col >> 10, c = col & 1023, h = c >> 6, d = c & 63;
        int b = rbase >> 11, t = rbase & (T_ - 1);
        if (sec == 0) {          // Q, fold softmax scale 1/sqrt(64)
#pragma unroll
          for (int r = 0; r < 4; ++r)
            outQ[(((size_t)b*H_ + h)*T_ + (t + r))*HD_ + d] = f2b((acc[i][j][r] + bv) * 0.125f);
        } else if (sec == 1) {   // K
#pragma unroll
          for (int r = 0; r < 4; ++r)
            outK[(((size_t)b*H_ + h)*T_ + (t + r))*HD_ + d] = f2b(acc[i][j][r] + bv);
        } else {                 // V transposed [B,H,hd,T]; 4 consecutive t -> one 8B store
          ushort4 pk;
          pk.x = f2b(acc[i][j][0] + bv);
          pk.y = f2b(acc[i][j][1] + bv);
          pk.z = f2b(acc[i][j][2] + bv);
          pk.w = f2b(acc[i][j][3] + bv);
          *(ushort4*)&outV[(((size_t)b*H_ + h)*HD_ + d)*T_ + t] = pk;
        }
      }
    }
  }
}

// ---------------- fused causal flash attention ----------------
// grid (T/128, B*H); 4 waves, each 32 q-rows. K/V tiles (64x64 bf16) in
// XOR-swizzled LDS (unit ^= row&7 within 128B rows -> 2-way max).
__global__ __launch_bounds__(256) void attn_fused(
    const unsigned short* __restrict__ Q,    // [BH][T][64], scale folded
    const unsigned short* __restrict__ Kc,   // [BH][T][64]
    const unsigned short* __restrict__ Vt,   // [BH][64][T]
    unsigned short* __restrict__ Y)          // [B][T][C] bf16
{
  __shared__ __align__(16) unsigned short Kl[64*64];
  __shared__ __align__(16) unsigned short Vl[64*64];
  __shared__ __align__(16) unsigned short Pl[4][32*64];
  const int tid = threadIdx.x, lane = tid & 63, w = tid >> 6;
  const int r16 = lane & 15, u = lane >> 4;
  const int q0 = blockIdx.x * 128;
  const int bh = blockIdx.y;
  const int b = bh >> 4, h = bh & 15;
  const int qw = q0 + w*32;

  const unsigned short* Qb = Q  + ((size_t)bh*T_ + qw)*HD_;
  const unsigned short* Kb = Kc + (size_t)bh*T_*HD_;
  const unsigned short* Vb = Vt + (size_t)bh*HD_*T_;

  // Q fragments in registers: lane holds Q[fm*16+r16][kk*32 + u*8 ..+7]
  bf16x8 qf[2][2];
#pragma unroll
  for (int fm = 0; fm < 2; ++fm)
#pragma unroll
    for (int kk = 0; kk < 2; ++kk)
      qf[fm][kk] = *(const bf16x8*)&Qb[(size_t)(fm*16 + r16)*HD_ + kk*32 + u*8];

  f32x4 o[2][4];
  float mr[2][4], lr[2][4];
#pragma unroll
  for (int fm = 0; fm < 2; ++fm) {
#pragma unroll
    for (int fd = 0; fd < 4; ++fd) o[fm][fd] = (f32x4)0.0f;
#pragma unroll
    for (int jr = 0; jr < 4; ++jr) { mr[fm][jr] = -1e30f; lr[fm][jr] = 0.0f; }
  }

  const int ntiles = (q0 >> 6) + 2;

  bf16x8 kr[2], vr[2], kr2[2], vr2[2];
  // prologue: stage tile 0 (reg -> swizzled LDS)
#pragma unroll
  for (int p = 0; p < 2; ++p) {
    int idx = p*256 + tid;
    int row = idx >> 3, un = idx & 7;
    kr[p] = *(const bf16x8*)&Kb[(size_t)row*HD_ + un*8];
    vr[p] = *(const bf16x8*)&Vb[(size_t)row*T_ + un*8];
  }
#pragma unroll
  for (int p = 0; p < 2; ++p) {
    int idx = p*256 + tid;
    int row = idx >> 3, un = idx & 7;
    int wu = un ^ (row & 7);
    *(bf16x8*)&Kl[row*64 + wu*8] = kr[p];
    *(bf16x8*)&Vl[row*64 + wu*8] = vr[p];
  }
  __syncthreads();

  for (int t = 0; t < ntiles; ++t) {
    const int kv0 = t * 64;
    const bool pre = (t + 1 < ntiles);
    if (pre) {  // issue next-tile global loads early; barrier drains them after compute
      const int kvn = kv0 + 64;
#pragma unroll
      for (int p = 0; p < 2; ++p) {
        int idx = p*256 + tid;
        int row = idx >> 3, un = idx & 7;
        kr2[p] = *(const bf16x8*)&Kb[(size_t)(kvn + row)*HD_ + un*8];
        vr2[p] = *(const bf16x8*)&Vb[(size_t)row*T_ + kvn + un*8];
      }
    }
    if (kv0 <= qw + 31) {   // causal: skip tiles fully above this wave's rows
      // S = Q K^T
      f32x4 s[2][4];
#pragma unroll
      for (int fm = 0; fm < 2; ++fm)
#pragma unroll
        for (int fn = 0; fn < 4; ++fn) s[fm][fn] = (f32x4)0.0f;
#pragma unroll
      for (int fn = 0; fn < 4; ++fn) {
        int rk = fn*16 + r16;
#pragma unroll
        for (int kk = 0; kk < 2; ++kk) {
          int un = (kk*4 + u) ^ (rk & 7);
          bf16x8 kf = *(const bf16x8*)&Kl[rk*64 + un*8];
          s[0][fn] = __builtin_amdgcn_mfma_f32_16x16x32_bf16(qf[0][kk], kf, s[0][fn], 0,0,0);
          s[1][fn] = __builtin_amdgcn_mfma_f32_16x16x32_bf16(qf[1][kk], kf, s[1][fn], 0,0,0);
        }
      }
      // causal mask on diagonal tiles
      if (kv0 + 63 > qw) {
#pragma unroll
        for (int fm = 0; fm < 2; ++fm)
#pragma unroll
          for (int fn = 0; fn < 4; ++fn) {
            int kv = kv0 + fn*16 + r16;
#pragma unroll
            for (int jr = 0; jr < 4; ++jr) {
              int q = qw + fm*16 + u*4 + jr;
              if (kv > q) s[fm][fn][jr] = -1e30f;
            }
          }
      }
      // online softmax: rows live on 16-lane groups (row = u*4+jr)
      float mt[2][4];
#pragma unroll
      for (int fm = 0; fm < 2; ++fm)
#pragma unroll
        for (int jr = 0; jr < 4; ++jr)
          mt[fm][jr] = fmaxf(fmaxf(s[fm][0][jr], s[fm][1][jr]), fmaxf(s[fm][2][jr], s[fm][3][jr]));
#pragma unroll
      for (int msk = 1; msk < 16; msk <<= 1)
#pragma unroll
        for (int fm = 0; fm < 2; ++fm)
#pragma unroll
          for (int jr = 0; jr < 4; ++jr)
            mt[fm][jr] = fmaxf(mt[fm][jr], __shfl_xor(mt[fm][jr], msk, 64));
      float alpha[2][4], rs[2][4];
#pragma unroll
      for (int fm = 0; fm < 2; ++fm)
#pragma unroll
        for (int jr = 0; jr < 4; ++jr) {
          float mn = fmaxf(mr[fm][jr], mt[fm][jr]);
          alpha[fm][jr] = __expf(mr[fm][jr] - mn);
          mr[fm][jr] = mn;
          rs[fm][jr] = 0.0f;
        }
      // P = exp(S-m): accumulate row-sum, write bf16 P to per-wave swizzled LDS
#pragma unroll
      for (int fm = 0; fm < 2; ++fm)
#pragma unroll
        for (int fn = 0; fn < 4; ++fn) {
          int kvc = fn*16 + r16;
#pragma unroll
          for (int jr = 0; jr < 4; ++jr) {
            float p = __expf(s[fm][fn][jr] - mr[fm][jr]);
            rs[fm][jr] += p;
            int qloc = fm*16 + u*4 + jr;
            int boff = qloc*128 + ((kvc*2) ^ ((qloc & 7) << 4));
            *(unsigned short*)((char*)&Pl[w][0] + boff) = f2b(p);
          }
        }
#pragma unroll
      for (int msk = 1; msk < 16; msk <<= 1)
#pragma unroll
        for (int fm = 0; fm < 2; ++fm)
#pragma unroll
          for (int jr = 0; jr < 4; ++jr)
            rs[fm][jr] += __shfl_xor(rs[fm][jr], msk, 64);
#pragma unroll
      for (int fm = 0; fm < 2; ++fm)
#pragma unroll
        for (int jr = 0; jr < 4; ++jr)
          lr[fm][jr] = lr[fm][jr]*alpha[fm][jr] + rs[fm][jr];
#pragma unroll
      for (int fm = 0; fm < 2; ++fm)
#pragma unroll
        for (int fd = 0; fd < 4; ++fd)
#pragma unroll
          for (int jr = 0; jr < 4; ++jr)
            o[fm][fd][jr] *= alpha[fm][jr];
      // O += P V
#pragma unroll
      for (int kks = 0; kks < 2; ++kks) {
        bf16x8 pa[2];
#pragma unroll
        for (int fm = 0; fm < 2; ++fm) {
          int rq = fm*16 + r16;
          int un = (kks*4 + u) ^ (rq & 7);
          pa[fm] = *(const bf16x8*)&Pl[w][rq*64 + un*8];
        }
#pragma unroll
        for (int fd = 0; fd < 4; ++fd) {
          int rv = fd*16 + r16;
          int un = (kks*4 + u) ^ (rv & 7);
          bf16x8 vf = *(const bf16x8*)&Vl[rv*64 + un*8];
          o[0][fd] = __builtin_amdgcn_mfma_f32_16x16x32_bf16(pa[0], vf, o[0][fd], 0,0,0);
          o[1][fd] = __builtin_amdgcn_mfma_f32_16x16x32_bf16(pa[1], vf, o[1][fd], 0,0,0);
        }
      }
    }
    __syncthreads();               // all waves done reading Kl/Vl
    if (pre) {
#pragma unroll
      for (int p = 0; p < 2; ++p) {
        int idx = p*256 + tid;
        int row = idx >> 3, un = idx & 7;
        int wu = un ^ (row & 7);
        *(bf16x8*)&Kl[row*64 + wu*8] = kr2[p];
        *(bf16x8*)&Vl[row*64 + wu*8] = vr2[p];
      }
      __syncthreads();             // next tile staged
    }
  }

  // epilogue: Y[b][t][h*64+d] = O / l
#pragma unroll
  for (int fm = 0; fm < 2; ++fm) {
    int tb = qw + fm*16 + u*4;
#pragma unroll
    for (int jr = 0; jr < 4; ++jr) {
      float inv = 1.0f / lr[fm][jr];
      int tt = tb + jr;
#pragma unroll
      for (int fd = 0; fd < 4; ++fd) {
        int c = h*64 + fd*16 + r16;
        Y[((size_t)b*T_ + tt)*C_ + c] = f2b(o[fm][fd][jr] * inv);
      }
    }
  }
}

// ---------------- launch ----------------
extern "C" void kernel_launch(void* const* d_in, const int* in_sizes, int n_in,
                              void* d_out, int out_size, void* d_ws, size_t ws_size,
                              hipStream_t stream) {
  const float* x      = (const float*)d_in[0];
  const float* W_attn = (const float*)d_in[1];
  const float* b_attn = (const float*)d_in[2];
  const float* W_proj = (const float*)d_in[3];
  const float* b_proj = (const float*)d_in[4];
  float* out = (float*)d_out;

  char* ws = (char*)d_ws;
  unsigned short* xb  = (unsigned short*)(ws);               // 16MB x bf16; reused as Y after QKV GEMM
  unsigned short* Wta = (unsigned short*)(ws + (16u << 20)); // 6MB  W_attn^T bf16 [3072][1024]
  unsigned short* Wtp = (unsigned short*)(ws + (22u << 20)); // 2MB  W_proj^T bf16 [1024][1024]
  unsigned short* qb  = (unsigned short*)(ws + (24u << 20)); // 16MB Q [BH][T][64]
  unsigned short* kb  = (unsigned short*)(ws + (40u << 20)); // 16MB K [BH][T][64]
  unsigned short* vtb = (unsigned short*)(ws + (56u << 20)); // 16MB V^T [BH][64][T]   (total 72MB)

  cvt_f32_bf16<<<2048, 256, 0, stream>>>(x, xb, (4 * T_ * C_) / 4);
  transpose_cvt<<<dim3(C_/32, (3*C_)/32), 256, 0, stream>>>(W_attn, Wta, C_, 3*C_);
  transpose_cvt<<<dim3(C_/32, C_/32), 256, 0, stream>>>(W_proj, Wtp, C_, C_);
  gemm128<1><<<dim3(64, 24), 256, 0, stream>>>(xb, Wta, b_attn, nullptr, qb, kb, vtb, 8192, 3072, 1024);
  attn_fused<<<dim3(T_/128, 64), 256, 0, stream>>>(qb, kb, vtb, xb);
  gemm128<0><<<dim3(64, 8), 256, 0, stream>>>(xb, Wtp, b_proj, out, nullptr, nullptr, nullptr, 8192, 1024, 1024);
}